// Round 3
// baseline (474.102 us; speedup 1.0000x reference)
//
#include <hip/hip_runtime.h>

typedef __attribute__((ext_vector_type(4))) float f32x4;
typedef __attribute__((ext_vector_type(8))) short short8;
typedef unsigned short u16;
typedef unsigned int u32;

#define NTOK 8192
#define DIM 512
#define FDIM 2048

// ---------- helpers ----------
__device__ inline u16 f2bf(float f) {
  u32 u = __builtin_bit_cast(u32, f);
  return (u16)((u + 0x7fffu + ((u >> 16) & 1u)) >> 16);
}
__device__ inline u32 pack2(float lo, float hi) {
  return (u32)f2bf(lo) | ((u32)f2bf(hi) << 16);
}
__device__ inline float bflo(u32 u) { return __builtin_bit_cast(float, u << 16); }
__device__ inline float bfhi(u32 u) { return __builtin_bit_cast(float, u & 0xffff0000u); }

__device__ inline void mfma16(f32x4& d, short8 a, short8 b) {
  asm("v_mfma_f32_16x16x32_bf16 %0, %1, %2, %0" : "+v"(d) : "v"(a), "v"(b));
}

__device__ inline void async16(const void* g, void* l) {
  __builtin_amdgcn_global_load_lds((const __attribute__((address_space(1))) u32*)g,
                                   (__attribute__((address_space(3))) u32*)l, 16, 0, 0);
}

// ================= 256x256 deep-pipelined GEMM =================
// C = A(MxK) * Bt(NxK)^T, bf16 in, epilogue per MODE.
// 512 threads = 8 waves (2 M x 4 N); per-wave output 128x64.
// BK=32, 4-slot LDS ring (128 KiB), counted vmcnt(8) (never 0 in loop),
// raw s_barrier, setprio around MFMA, XOR-swizzled LDS reads with
// inverse-swizzled global_load_lds source, bijective XCD block swizzle.
// MODE 0: QKV fused (N=1536): +bias, q scaled, split q/k/v
// MODE 1: FF1: +bias, relu -> o0 (ld 2048)
// MODE 2: FF2: +bias -> o0 (ld 512)
template<int MODE>
__global__ __launch_bounds__(512, 2)
void gemm256_kernel(const u16* __restrict__ A, const u16* __restrict__ Bt,
                    int K,
                    const float* __restrict__ c0p, const float* __restrict__ c1p,
                    const float* __restrict__ c2p,
                    u16* __restrict__ o0, u16* __restrict__ o1, u16* __restrict__ o2)
{
  __shared__ u16 lds[4][2][256 * 32];   // [slot][A/B][row*32+col] ; 128 KiB
  const int tid = threadIdx.x;
  const int lane = tid & 63;
  const int w = tid >> 6;
  const int wr = w >> 2, wc = w & 3;

  // XCD-aware bijective block swizzle (nwg % 8 == 0 for all our grids)
  const int gx = gridDim.x;
  const int nwg = gx * gridDim.y;
  const int orig = blockIdx.y * gx + blockIdx.x;
  const int swz = (orig & 7) * (nwg >> 3) + (orig >> 3);
  const long bm = (long)(swz / gx) << 8;
  const long bn = (long)(swz % gx) << 8;

  const int nkt = K >> 5;

  const f32x4 z = {0.f, 0.f, 0.f, 0.f};
  f32x4 acc[8][4];
#pragma unroll
  for (int m = 0; m < 8; ++m)
#pragma unroll
    for (int n = 0; n < 4; ++n) acc[m][n] = z;

  // ---- staging mapping (linear LDS dest, inverse-swizzled global source) ----
  // per block-wide instr: 8 KiB = 128 rows x 64 B; wave w covers [w*1024, +1024)
  const int srow = (w << 4) + (lane >> 2);                      // row in chunk
  const int scol = ((((lane & 3) << 4) ^ (((lane >> 2) & 3) << 4)) >> 1); // elem col
  const u16* gA0 = A + (bm + srow) * (long)K + scol;
  const u16* gA1 = A + (bm + 128 + srow) * (long)K + scol;
  const u16* gB0 = Bt + (bn + srow) * (long)K + scol;
  const u16* gB1 = Bt + (bn + 128 + srow) * (long)K + scol;
  const int ldst = w << 9;   // u16 index of wave's 1 KiB slice

  // prologue: stage K-tiles 0,1,2 into slots 0,1,2 (A,A,B,B per kt)
#pragma unroll
  for (int t = 0; t < 3; ++t) {
    const long ko = (long)t << 5;
    async16(gA0 + ko, &lds[t][0][ldst]);
    async16(gA1 + ko, &lds[t][0][4096 + ldst]);
    async16(gB0 + ko, &lds[t][1][ldst]);
    async16(gB1 + ko, &lds[t][1][4096 + ldst]);
  }
  asm volatile("s_waitcnt vmcnt(8)" ::: "memory");   // kt0 landed
  __builtin_amdgcn_s_barrier();

  // ---- fragment read addressing (swizzled col) ----
  const int rc = (((lane >> 4) ^ (lane & 3)) << 3);  // swizzled col (elems)
  const int ar0 = wr * 128 + (lane & 15);
  const int br0 = wc * 64 + (lane & 15);

  for (int n = 0; n < nkt; ++n) {
    const int s = n & 3;
    const int sn = (n + 3) & 3;
    const bool pre = (n + 3 < nkt);
    const long ko = (long)(n + 3) << 5;

    // ======== phase A: A(m0..3) + B(n0..3) reads, stage next-A ========
    short8 a0 = *(const short8*)&lds[s][0][(ar0 + 0) * 32 + rc];
    short8 a1 = *(const short8*)&lds[s][0][(ar0 + 16) * 32 + rc];
    short8 a2 = *(const short8*)&lds[s][0][(ar0 + 32) * 32 + rc];
    short8 a3 = *(const short8*)&lds[s][0][(ar0 + 48) * 32 + rc];
    short8 b0 = *(const short8*)&lds[s][1][(br0 + 0) * 32 + rc];
    short8 b1 = *(const short8*)&lds[s][1][(br0 + 16) * 32 + rc];
    short8 b2 = *(const short8*)&lds[s][1][(br0 + 32) * 32 + rc];
    short8 b3 = *(const short8*)&lds[s][1][(br0 + 48) * 32 + rc];
    if (pre) {
      async16(gA0 + ko, &lds[sn][0][ldst]);
      async16(gA1 + ko, &lds[sn][0][4096 + ldst]);
    }
    __builtin_amdgcn_s_barrier();
    asm volatile("s_waitcnt lgkmcnt(0)" ::: "memory");
    __builtin_amdgcn_sched_barrier(0);
    __builtin_amdgcn_s_setprio(1);
    mfma16(acc[0][0], a0, b0); mfma16(acc[0][1], a0, b1);
    mfma16(acc[0][2], a0, b2); mfma16(acc[0][3], a0, b3);
    mfma16(acc[1][0], a1, b0); mfma16(acc[1][1], a1, b1);
    mfma16(acc[1][2], a1, b2); mfma16(acc[1][3], a1, b3);
    mfma16(acc[2][0], a2, b0); mfma16(acc[2][1], a2, b1);
    mfma16(acc[2][2], a2, b2); mfma16(acc[2][3], a2, b3);
    mfma16(acc[3][0], a3, b0); mfma16(acc[3][1], a3, b1);
    mfma16(acc[3][2], a3, b2); mfma16(acc[3][3], a3, b3);
    __builtin_amdgcn_s_setprio(0);
    __builtin_amdgcn_s_barrier();

    // ======== phase B: A(m4..7) reads, stage next-B ========
    short8 a4 = *(const short8*)&lds[s][0][(ar0 + 64) * 32 + rc];
    short8 a5 = *(const short8*)&lds[s][0][(ar0 + 80) * 32 + rc];
    short8 a6 = *(const short8*)&lds[s][0][(ar0 + 96) * 32 + rc];
    short8 a7 = *(const short8*)&lds[s][0][(ar0 + 112) * 32 + rc];
    if (pre) {
      async16(gB0 + ko, &lds[sn][1][ldst]);
      async16(gB1 + ko, &lds[sn][1][4096 + ldst]);
    }
    __builtin_amdgcn_s_barrier();
    asm volatile("s_waitcnt lgkmcnt(0)" ::: "memory");
    __builtin_amdgcn_sched_barrier(0);
    __builtin_amdgcn_s_setprio(1);
    mfma16(acc[4][0], a4, b0); mfma16(acc[4][1], a4, b1);
    mfma16(acc[4][2], a4, b2); mfma16(acc[4][3], a4, b3);
    mfma16(acc[5][0], a5, b0); mfma16(acc[5][1], a5, b1);
    mfma16(acc[5][2], a5, b2); mfma16(acc[5][3], a5, b3);
    mfma16(acc[6][0], a6, b0); mfma16(acc[6][1], a6, b1);
    mfma16(acc[6][2], a6, b2); mfma16(acc[6][3], a6, b3);
    mfma16(acc[7][0], a7, b0); mfma16(acc[7][1], a7, b1);
    mfma16(acc[7][2], a7, b2); mfma16(acc[7][3], a7, b3);
    __builtin_amdgcn_s_setprio(0);
    // counted vmcnt: kt n+1 guaranteed landed; never 0 in steady state
    if (n + 3 < nkt)      asm volatile("s_waitcnt vmcnt(8)" ::: "memory");
    else if (n + 2 < nkt) asm volatile("s_waitcnt vmcnt(4)" ::: "memory");
    else if (n + 1 < nkt) asm volatile("s_waitcnt vmcnt(0)" ::: "memory");
    __builtin_amdgcn_s_barrier();
  }
  asm volatile("s_nop 7\n s_nop 7");

  // ---- epilogue ----
  const long r0 = bm + wr * 128 + ((lane >> 4) << 2);
  const long c0 = bn + wc * 64 + (lane & 15);
#pragma unroll
  for (int m = 0; m < 8; ++m) {
#pragma unroll
    for (int n = 0; n < 4; ++n) {
      const long col = c0 + n * 16;
#pragma unroll
      for (int r = 0; r < 4; ++r) {
        const long row = r0 + m * 16 + r;
        float v = acc[m][n][r];
        if (MODE == 0) {
          if (col < 512) {
            o0[row * 512 + col] = f2bf((v + c0p[col]) * 0.044194173824159216f);
          } else if (col < 1024) {
            o1[row * 512 + (col - 512)] = f2bf(v + c1p[col - 512]);
          } else {
            o2[row * 512 + (col - 1024)] = f2bf(v + c2p[col - 1024]);
          }
        } else if (MODE == 1) {
          v += c0p[col];
          o0[row * 2048 + col] = f2bf(fmaxf(v, 0.f));
        } else {
          v += c0p[col];
          o0[row * 512 + col] = f2bf(v);
        }
      }
    }
  }
}

// ---------- local attention: one block = one (batch, window) ----------
__global__ __launch_bounds__(256, 2)
void attn_kernel(const u16* __restrict__ q, const u16* __restrict__ k,
                 const u16* __restrict__ vt, u16* __restrict__ ao)
{
  __shared__ __align__(16) char smem[46080];
  u16 (*P)[200] = (u16(*)[200])smem;            // 64 x 200 bf16 = 25600 B
  u16 (*qa)[40] = (u16(*)[40])(smem + 25600);   // 64 x 40
  u16 (*ka)[40] = (u16(*)[40])(smem + 30720);   // 192 x 40
  u16 (*vb)[40] = (u16(*)[40])(smem + 25600);   // 256 x 40 (phase 2)

  const int tid = threadIdx.x, lane = tid & 63, wq = tid >> 6;
  const int w = blockIdx.x, b = blockIdx.y;
  const long qrow0 = (long)b * NTOK + w * 64;
  const int tk0 = w * 64 - 64;

  const f32x4 z = {0.f, 0.f, 0.f, 0.f};
  f32x4 sacc[12];
#pragma unroll
  for (int n = 0; n < 12; ++n) sacc[n] = z;

  const int srow = tid >> 2, sc8 = (tid & 3) << 3;

  for (int dt = 0; dt < 16; ++dt) {
    const int d0 = dt << 5;
    *(uint4*)&qa[srow][sc8] = *(const uint4*)&q[(qrow0 + srow) * DIM + d0 + sc8];
#pragma unroll
    for (int i = 0; i < 3; ++i) {
      const int idx = i * 256 + tid;
      const int r = idx >> 2, c8 = (idx & 3) << 3;
      const int t = tk0 + r;
      uint4 val = {0u, 0u, 0u, 0u};
      if (t >= 0 && t < NTOK)
        val = *(const uint4*)&k[((long)b * NTOK + t) * DIM + d0 + c8];
      *(uint4*)&ka[r][c8] = val;
    }
    __syncthreads();
    const short8 af = *(const short8*)&qa[wq * 16 + (lane & 15)][(lane >> 4) << 3];
#pragma unroll
    for (int n = 0; n < 12; ++n) {
      const short8 bv = *(const short8*)&ka[n * 16 + (lane & 15)][(lane >> 4) << 3];
      mfma16(sacc[n], af, bv);
    }
    __syncthreads();
  }
  asm volatile("s_nop 7\n s_nop 7\n s_nop 7");

  const int cbase = lane & 15;
  const int rgrp = (lane >> 4) << 2;
#pragma unroll
  for (int r = 0; r < 4; ++r) {
    float sv[12];
    float mx = -3.0e38f;
#pragma unroll
    for (int n = 0; n < 12; ++n) {
      const int t = tk0 + n * 16 + cbase;
      const float s = (t >= 0 && t < NTOK) ? sacc[n][r] : -1.0e10f;
      sv[n] = s;
      mx = fmaxf(mx, s);
    }
#pragma unroll
    for (int off = 1; off < 16; off <<= 1) mx = fmaxf(mx, __shfl_xor(mx, off, 64));
    float sum = 0.f;
#pragma unroll
    for (int n = 0; n < 12; ++n) { sv[n] = __expf(sv[n] - mx); sum += sv[n]; }
#pragma unroll
    for (int off = 1; off < 16; off <<= 1) sum += __shfl_xor(sum, off, 64);
    const float inv = 1.f / sum;
#pragma unroll
    for (int n = 0; n < 12; ++n)
      P[wq * 16 + rgrp + r][n * 16 + cbase] = f2bf(sv[n] * inv);
  }
  __syncthreads();

  short8 pf[6];
#pragma unroll
  for (int kt = 0; kt < 6; ++kt)
    pf[kt] = *(const short8*)&P[wq * 16 + (lane & 15)][kt * 32 + ((lane >> 4) << 3)];

  f32x4 oacc[32];
#pragma unroll
  for (int n = 0; n < 32; ++n) oacc[n] = z;

#pragma unroll
  for (int dh = 0; dh < 2; ++dh) {
#pragma unroll
    for (int kt = 0; kt < 6; ++kt) {
#pragma unroll
      for (int i = 0; i < 4; ++i) {
        const int idx = i * 256 + tid;
        const int dr = idx >> 2, c8 = (idx & 3) << 3;
        const int t = tk0 + kt * 32 + c8;
        uint4 val = {0u, 0u, 0u, 0u};
        if (t >= 0 && t < NTOK)
          val = *(const uint4*)&vt[((long)b * DIM + dh * 256 + dr) * NTOK + t];
        *(uint4*)&vb[dr][c8] = val;
      }
      __syncthreads();
#pragma unroll
      for (int nn = 0; nn < 16; ++nn) {
        const short8 bv = *(const short8*)&vb[nn * 16 + (lane & 15)][(lane >> 4) << 3];
        mfma16(oacc[dh * 16 + nn], pf[kt], bv);
      }
      __syncthreads();
    }
  }
  asm volatile("s_nop 7\n s_nop 7\n s_nop 7");

#pragma unroll
  for (int n = 0; n < 32; ++n) {
    const int d = n * 16 + cbase;
#pragma unroll
    for (int r = 0; r < 4; ++r) {
      const long row = qrow0 + wq * 16 + rgrp + r;
      ao[row * DIM + d] = f2bf(oacc[n][r]);
    }
  }
}

// ---------- fused residual + LayerNorm, one wave per row ----------
template<int V>
__global__ __launch_bounds__(256)
void ln_kernel(const float* __restrict__ af, const u16* __restrict__ abf,
               const u16* __restrict__ bbf,
               const float* __restrict__ g, const float* __restrict__ bb,
               u16* __restrict__ obf, float* __restrict__ of)
{
  const int lane = threadIdx.x & 63;
  const long row = (long)blockIdx.x * 4 + (threadIdx.x >> 6);
  const long base = row * DIM + lane * 8;
  float x[8];
  if (V == 1) {
    const float4 u0 = *(const float4*)(af + base);
    const float4 u1 = *(const float4*)(af + base + 4);
    const uint4 ub = *(const uint4*)(bbf + base);
    x[0] = u0.x + bflo(ub.x); x[1] = u0.y + bfhi(ub.x);
    x[2] = u0.z + bflo(ub.y); x[3] = u0.w + bfhi(ub.y);
    x[4] = u1.x + bflo(ub.z); x[5] = u1.y + bfhi(ub.z);
    x[6] = u1.z + bflo(ub.w); x[7] = u1.w + bfhi(ub.w);
  } else {
    const uint4 ua = *(const uint4*)(abf + base);
    const uint4 ub = *(const uint4*)(bbf + base);
    x[0] = bflo(ua.x) + bflo(ub.x); x[1] = bfhi(ua.x) + bfhi(ub.x);
    x[2] = bflo(ua.y) + bflo(ub.y); x[3] = bfhi(ua.y) + bfhi(ub.y);
    x[4] = bflo(ua.z) + bflo(ub.z); x[5] = bfhi(ua.z) + bfhi(ub.z);
    x[6] = bflo(ua.w) + bflo(ub.w); x[7] = bfhi(ua.w) + bfhi(ub.w);
  }
  float s = 0.f, sq = 0.f;
#pragma unroll
  for (int i = 0; i < 8; ++i) { s += x[i]; sq += x[i] * x[i]; }
#pragma unroll
  for (int off = 1; off < 64; off <<= 1) {
    s += __shfl_xor(s, off, 64);
    sq += __shfl_xor(sq, off, 64);
  }
  const float mean = s * (1.f / 512.f);
  const float var = fmaxf(sq * (1.f / 512.f) - mean * mean, 0.f);
  const float rs = rsqrtf(var + 1e-5f);
  const int db = lane * 8;
  const float4 g0 = *(const float4*)(g + db);
  const float4 g1 = *(const float4*)(g + db + 4);
  const float4 b0 = *(const float4*)(bb + db);
  const float4 b1 = *(const float4*)(bb + db + 4);
  float y[8];
  y[0] = (x[0] - mean) * rs * g0.x + b0.x; y[1] = (x[1] - mean) * rs * g0.y + b0.y;
  y[2] = (x[2] - mean) * rs * g0.z + b0.z; y[3] = (x[3] - mean) * rs * g0.w + b0.w;
  y[4] = (x[4] - mean) * rs * g1.x + b1.x; y[5] = (x[5] - mean) * rs * g1.y + b1.y;
  y[6] = (x[6] - mean) * rs * g1.z + b1.z; y[7] = (x[7] - mean) * rs * g1.w + b1.w;
  if (V == 1) {
    uint4 o = { pack2(y[0], y[1]), pack2(y[2], y[3]), pack2(y[4], y[5]), pack2(y[6], y[7]) };
    *(uint4*)(obf + base) = o;
  } else {
    float4 o0v = {y[0], y[1], y[2], y[3]}, o1v = {y[4], y[5], y[6], y[7]};
    *(float4*)(of + base) = o0v;
    *(float4*)(of + base + 4) = o1v;
  }
}

// ---------- f32 -> bf16 convert ----------
__global__ __launch_bounds__(256)
void cvt_src_kernel(const float* __restrict__ in, u16* __restrict__ out)
{
  const long i = ((long)blockIdx.x * 256 + threadIdx.x) * 8;
  const float4 a = *(const float4*)(in + i);
  const float4 c = *(const float4*)(in + i + 4);
  uint4 o = { pack2(a.x, a.y), pack2(a.z, a.w), pack2(c.x, c.y), pack2(c.z, c.w) };
  *(uint4*)(out + i) = o;
}

// ---------- transpose f32(RxC) -> bf16(CxR) ----------
__global__ __launch_bounds__(256)
void transpose_cvt_kernel(const float* __restrict__ in, u16* __restrict__ out,
                          int R, int C)
{
  __shared__ float tile[32][33];
  const int tx = threadIdx.x & 31, ty = threadIdx.x >> 5;
  const long c = (long)blockIdx.x * 32 + tx;
#pragma unroll
  for (int i = 0; i < 4; ++i) {
    const long r = (long)blockIdx.y * 32 + ty + i * 8;
    tile[ty + i * 8][tx] = in[r * C + c];
  }
  __syncthreads();
#pragma unroll
  for (int i = 0; i < 4; ++i) {
    const int cc = ty + i * 8;
    out[((long)blockIdx.x * 32 + cc) * R + (long)blockIdx.y * 32 + tx] = f2bf(tile[tx][cc]);
  }
}

// ---------- transpose bf16(RxC) -> bf16(CxR), batched over z ----------
__global__ __launch_bounds__(256)
void transpose_bf_kernel(const u16* __restrict__ in, u16* __restrict__ out,
                         int R, int C)
{
  __shared__ u16 tile[32][33];
  const long bo = (long)blockIdx.z * R * C;
  const int tx = threadIdx.x & 31, ty = threadIdx.x >> 5;
  const long c = (long)blockIdx.x * 32 + tx;
#pragma unroll
  for (int i = 0; i < 4; ++i) {
    const long r = (long)blockIdx.y * 32 + ty + i * 8;
    tile[ty + i * 8][tx] = in[bo + r * C + c];
  }
  __syncthreads();
#pragma unroll
  for (int i = 0; i < 4; ++i) {
    const int cc = ty + i * 8;
    out[bo + ((long)blockIdx.x * 32 + cc) * R + (long)blockIdx.y * 32 + tx] = tile[tx][cc];
  }
}

extern "C" void kernel_launch(void* const* d_in, const int* in_sizes, int n_in,
                              void* d_out, int out_size, void* d_ws, size_t ws_size,
                              hipStream_t stream) {
  const float* src  = (const float*)d_in[0];
  const float* Wq   = (const float*)d_in[2];
  const float* bq   = (const float*)d_in[3];
  const float* Wk   = (const float*)d_in[4];
  const float* bk   = (const float*)d_in[5];
  const float* Wv   = (const float*)d_in[6];
  const float* bv   = (const float*)d_in[7];
  const float* ln1g = (const float*)d_in[8];
  const float* ln1b = (const float*)d_in[9];
  const float* W1   = (const float*)d_in[10];
  const float* b1   = (const float*)d_in[11];
  const float* W2   = (const float*)d_in[12];
  const float* b2   = (const float*)d_in[13];
  const float* ln2g = (const float*)d_in[14];
  const float* ln2b = (const float*)d_in[15];
  float* out = (float*)d_out;

  // ---- workspace overlay (~134 MiB, proven in round 2) ----
  char* ws = (char*)d_ws;
  const size_t TD2 = (size_t)32768 * 512 * 2;   // 32 MiB
  u16* buf0 = (u16*)(ws + 0 * TD2);
  u16* buf1 = (u16*)(ws + 1 * TD2);
  u16* buf2 = (u16*)(ws + 2 * TD2);
  u16* buf3 = (u16*)(ws + 3 * TD2);
  u16* wT   = (u16*)(ws + 4 * TD2);
  u16* wqkvT = wT;                       // 1536 x 512
  u16* w1T   = wT + 1536 * 512;          // 2048 x 512
  u16* w2T   = w1T + (size_t)2048 * 512; // 512 x 2048

  u16* sbf = buf0;   // src bf16
  u16* qb  = buf1;   // q (scaled)
  u16* kb  = buf2;   // k
  u16* vbf = buf3;   // v
  u16* vtb = buf0;   // v^T [b][d][tok]  (sbf dead after QKV)
  u16* aob = buf3;   // attn_out         (v dead after transpose)
  u16* xb  = buf0;   // x bf16           (vt dead after attn)
  u16* hb  = buf2;   // FF hidden chunk, 16384x2048 = buf2+buf3
  u16* yb  = buf1;   // FF2 out          (q dead after attn)

  cvt_src_kernel<<<dim3(8192), 256, 0, stream>>>(src, sbf);
  transpose_cvt_kernel<<<dim3(16, 16), 256, 0, stream>>>(Wq, wqkvT, 512, 512);
  transpose_cvt_kernel<<<dim3(16, 16), 256, 0, stream>>>(Wk, wqkvT + 512 * 512, 512, 512);
  transpose_cvt_kernel<<<dim3(16, 16), 256, 0, stream>>>(Wv, wqkvT + 1024 * 512, 512, 512);
  transpose_cvt_kernel<<<dim3(64, 16), 256, 0, stream>>>(W1, w1T, 512, 2048);
  transpose_cvt_kernel<<<dim3(16, 64), 256, 0, stream>>>(W2, w2T, 2048, 512);

  // QKV: M=32768, N=1536, K=512 -> grid (6,128)
  gemm256_kernel<0><<<dim3(6, 128), 512, 0, stream>>>(sbf, wqkvT, 512,
                                                      bq, bk, bv, qb, kb, vbf);
  transpose_bf_kernel<<<dim3(16, 256, 4), 256, 0, stream>>>(vbf, vtb, 8192, 512);
  attn_kernel<<<dim3(128, 4), 256, 0, stream>>>(qb, kb, vtb, aob);
  ln_kernel<1><<<dim3(8192), 256, 0, stream>>>(src, nullptr, aob, ln1g, ln1b, xb, nullptr);

  // FF in two 16384-row chunks
  for (int c = 0; c < 2; ++c) {
    const size_t ro = (size_t)c * 16384;
    gemm256_kernel<1><<<dim3(8, 64), 512, 0, stream>>>(xb + ro * 512, w1T, 512,
                                                       b1, nullptr, nullptr, hb, nullptr, nullptr);
    gemm256_kernel<2><<<dim3(2, 64), 512, 0, stream>>>(hb, w2T, 2048,
                                                       b2, nullptr, nullptr, yb + ro * 512, nullptr, nullptr);
  }
  ln_kernel<2><<<dim3(8192), 256, 0, stream>>>(nullptr, xb, yb, ln2g, ln2b, nullptr, out);
}

// Round 4
// 427.977 us; speedup vs baseline: 1.1078x; 1.1078x over previous
//
#include <hip/hip_runtime.h>

typedef __attribute__((ext_vector_type(4))) float f32x4;
typedef __attribute__((ext_vector_type(8))) short short8;
typedef unsigned short u16;
typedef unsigned int u32;

#define NTOK 8192
#define DIM 512
#define FDIM 2048

// ---------- helpers ----------
__device__ inline u16 f2bf(float f) {
  u32 u = __builtin_bit_cast(u32, f);
  return (u16)((u + 0x7fffu + ((u >> 16) & 1u)) >> 16);
}
__device__ inline u32 pack2(float lo, float hi) {
  return (u32)f2bf(lo) | ((u32)f2bf(hi) << 16);
}
__device__ inline float bflo(u32 u) { return __builtin_bit_cast(float, u << 16); }
__device__ inline float bfhi(u32 u) { return __builtin_bit_cast(float, u & 0xffff0000u); }

__device__ inline void mfma16(f32x4& d, short8 a, short8 b) {
  asm("v_mfma_f32_16x16x32_bf16 %0, %1, %2, %0" : "+v"(d) : "v"(a), "v"(b));
}

__device__ inline void async16(const void* g, void* l) {
  __builtin_amdgcn_global_load_lds((const __attribute__((address_space(1))) u32*)g,
                                   (__attribute__((address_space(3))) u32*)l, 16, 0, 0);
}

// ================= 256x128 GEMM, 4 waves, per-wave 128x64 =================
// C = A(MxK) * Bt(NxK)^T, bf16. BK=32, 3-slot LDS ring (72 KiB, 2 blocks/CU),
// counted vmcnt(6), raw s_barrier, setprio, 2-way-free LDS swizzle:
// physical 16B slot = logical slot ^ ((row>>1)&3), applied to both the
// global_load_lds source (inverse) and the ds_read col.
// MODE 0: QKV fused (N=1536): +bias, q scaled, split q/k/v
// MODE 1: FF1: +bias, relu     MODE 2: FF2: +bias
template<int MODE>
__global__ __launch_bounds__(256, 2)
void gemm256_kernel(const u16* __restrict__ A, const u16* __restrict__ Bt,
                    int K,
                    const float* __restrict__ c0p, const float* __restrict__ c1p,
                    const float* __restrict__ c2p,
                    u16* __restrict__ o0, u16* __restrict__ o1, u16* __restrict__ o2)
{
  __shared__ u16 lds3[3][12288];   // [slot][A 256x32 | B 128x32] ; 72 KiB
  const int tid = threadIdx.x;
  const int lane = tid & 63;
  const int w = tid >> 6;
  const int wr = w >> 1, wc = w & 1;

  // XCD-aware bijective chunked block swizzle (nwg % 8 == 0 for all grids)
  const int gx = gridDim.x;
  const int nwg = gx * gridDim.y;
  const int orig = blockIdx.y * gx + blockIdx.x;
  const int swz = (orig & 7) * (nwg >> 3) + (orig >> 3);
  const long bm = (long)(swz / gx) << 8;    // 256-row tile
  const long bn = (long)(swz % gx) << 7;    // 128-col tile

  const int nkt = K >> 5;

  const f32x4 z = {0.f, 0.f, 0.f, 0.f};
  f32x4 acc[8][4];
#pragma unroll
  for (int m = 0; m < 8; ++m)
#pragma unroll
    for (int n = 0; n < 4; ++n) acc[m][n] = z;

  // ---- staging: per wave 4 A-instrs (rows 16*(4w+j)) + 2 B-instrs ----
  // lane l: row_in_instr = l>>2 ; global col pre-swizzled so that linear LDS
  // write (base + l*16B) lands logical slot (l&3)^((row>>1)&3) at physical l&3.
  const int srow = lane >> 2;
  const int scol = (((lane & 3) ^ ((lane >> 3) & 3)) << 3);
  const u16* gA[4];
  const u16* gB[2];
  int aoff[4], boff[2];
#pragma unroll
  for (int j = 0; j < 4; ++j) {
    const int i = 4 * w + j;
    gA[j] = A + (bm + 16 * i + srow) * (long)K + scol;
    aoff[j] = i * 512;                 // u16 index: row*32, 16 rows per instr
  }
#pragma unroll
  for (int j = 0; j < 2; ++j) {
    const int i = 2 * w + j;
    gB[j] = Bt + (bn + 16 * i + srow) * (long)K + scol;
    boff[j] = 8192 + i * 512;
  }

  auto stage = [&](int kt, int s) {
    const long ko = (long)kt << 5;
#pragma unroll
    for (int j = 0; j < 4; ++j) async16(gA[j] + ko, &lds3[s][aoff[j]]);
#pragma unroll
    for (int j = 0; j < 2; ++j) async16(gB[j] + ko, &lds3[s][boff[j]]);
  };

  // prologue: tiles 0,1 -> slots 0,1
  stage(0, 0);
  stage(1, 1);
  asm volatile("s_waitcnt vmcnt(6)" ::: "memory");   // own tile-0 loads done
  __builtin_amdgcn_s_barrier();

  // ---- fragment read addressing (swizzled col) ----
  const int rc = (((lane >> 4) ^ ((lane >> 1) & 3)) << 3);
  const int ar = wr * 128 + (lane & 15);
  const int br = wc * 64 + (lane & 15);

  for (int n = 0; n < nkt; ++n) {
    const int s = n % 3;
    if (n + 2 < nkt) stage(n + 2, (n + 2) % 3);
    const u16* lp = lds3[s];
    short8 af[8], bfr[4];
#pragma unroll
    for (int m = 0; m < 8; ++m)
      af[m] = *(const short8*)&lp[(ar + m * 16) * 32 + rc];
#pragma unroll
    for (int nn = 0; nn < 4; ++nn)
      bfr[nn] = *(const short8*)&lp[8192 + (br + nn * 16) * 32 + rc];
    asm volatile("s_waitcnt lgkmcnt(0)" ::: "memory");
    __builtin_amdgcn_sched_barrier(0);
    __builtin_amdgcn_s_setprio(1);
#pragma unroll
    for (int m = 0; m < 8; ++m) {
      mfma16(acc[m][0], af[m], bfr[0]);
      mfma16(acc[m][1], af[m], bfr[1]);
      mfma16(acc[m][2], af[m], bfr[2]);
      mfma16(acc[m][3], af[m], bfr[3]);
    }
    __builtin_amdgcn_s_setprio(0);
    if (n + 2 < nkt)      asm volatile("s_waitcnt vmcnt(6)" ::: "memory");
    else if (n + 1 < nkt) asm volatile("s_waitcnt vmcnt(0)" ::: "memory");
    __builtin_amdgcn_s_barrier();
  }
  asm volatile("s_nop 7\n s_nop 7");

  // ---- epilogue ----
  const long r0 = bm + wr * 128 + ((lane >> 4) << 2);
  const long c0 = bn + wc * 64 + (lane & 15);
#pragma unroll
  for (int m = 0; m < 8; ++m) {
#pragma unroll
    for (int n = 0; n < 4; ++n) {
      const long col = c0 + n * 16;
#pragma unroll
      for (int r = 0; r < 4; ++r) {
        const long row = r0 + m * 16 + r;
        float v = acc[m][n][r];
        if (MODE == 0) {
          if (col < 512) {
            o0[row * 512 + col] = f2bf((v + c0p[col]) * 0.044194173824159216f);
          } else if (col < 1024) {
            o1[row * 512 + (col - 512)] = f2bf(v + c1p[col - 512]);
          } else {
            o2[row * 512 + (col - 1024)] = f2bf(v + c2p[col - 1024]);
          }
        } else if (MODE == 1) {
          v += c0p[col];
          o0[row * 2048 + col] = f2bf(fmaxf(v, 0.f));
        } else {
          v += c0p[col];
          o0[row * 512 + col] = f2bf(v);
        }
      }
    }
  }
}

// ---------- local attention: one block = one (batch, window) ----------
__global__ __launch_bounds__(256, 2)
void attn_kernel(const u16* __restrict__ q, const u16* __restrict__ k,
                 const u16* __restrict__ vt, u16* __restrict__ ao)
{
  __shared__ __align__(16) char smem[46080];
  u16 (*P)[200] = (u16(*)[200])smem;            // 64 x 200 bf16 = 25600 B
  u16 (*qa)[40] = (u16(*)[40])(smem + 25600);   // 64 x 40
  u16 (*ka)[40] = (u16(*)[40])(smem + 30720);   // 192 x 40
  u16 (*vb)[40] = (u16(*)[40])(smem + 25600);   // 256 x 40 (phase 2)

  const int tid = threadIdx.x, lane = tid & 63, wq = tid >> 6;
  const int w = blockIdx.x, b = blockIdx.y;
  const long qrow0 = (long)b * NTOK + w * 64;
  const int tk0 = w * 64 - 64;

  const f32x4 z = {0.f, 0.f, 0.f, 0.f};
  f32x4 sacc[12];
#pragma unroll
  for (int n = 0; n < 12; ++n) sacc[n] = z;

  const int srow = tid >> 2, sc8 = (tid & 3) << 3;

  for (int dt = 0; dt < 16; ++dt) {
    const int d0 = dt << 5;
    *(uint4*)&qa[srow][sc8] = *(const uint4*)&q[(qrow0 + srow) * DIM + d0 + sc8];
#pragma unroll
    for (int i = 0; i < 3; ++i) {
      const int idx = i * 256 + tid;
      const int r = idx >> 2, c8 = (idx & 3) << 3;
      const int t = tk0 + r;
      uint4 val = {0u, 0u, 0u, 0u};
      if (t >= 0 && t < NTOK)
        val = *(const uint4*)&k[((long)b * NTOK + t) * DIM + d0 + c8];
      *(uint4*)&ka[r][c8] = val;
    }
    __syncthreads();
    const short8 af = *(const short8*)&qa[wq * 16 + (lane & 15)][(lane >> 4) << 3];
#pragma unroll
    for (int n = 0; n < 12; ++n) {
      const short8 bv = *(const short8*)&ka[n * 16 + (lane & 15)][(lane >> 4) << 3];
      mfma16(sacc[n], af, bv);
    }
    __syncthreads();
  }
  asm volatile("s_nop 7\n s_nop 7\n s_nop 7");

  const int cbase = lane & 15;
  const int rgrp = (lane >> 4) << 2;
#pragma unroll
  for (int r = 0; r < 4; ++r) {
    float sv[12];
    float mx = -3.0e38f;
#pragma unroll
    for (int n = 0; n < 12; ++n) {
      const int t = tk0 + n * 16 + cbase;
      const float s = (t >= 0 && t < NTOK) ? sacc[n][r] : -1.0e10f;
      sv[n] = s;
      mx = fmaxf(mx, s);
    }
#pragma unroll
    for (int off = 1; off < 16; off <<= 1) mx = fmaxf(mx, __shfl_xor(mx, off, 64));
    float sum = 0.f;
#pragma unroll
    for (int n = 0; n < 12; ++n) { sv[n] = __expf(sv[n] - mx); sum += sv[n]; }
#pragma unroll
    for (int off = 1; off < 16; off <<= 1) sum += __shfl_xor(sum, off, 64);
    const float inv = 1.f / sum;
#pragma unroll
    for (int n = 0; n < 12; ++n)
      P[wq * 16 + rgrp + r][n * 16 + cbase] = f2bf(sv[n] * inv);
  }
  __syncthreads();

  short8 pf[6];
#pragma unroll
  for (int kt = 0; kt < 6; ++kt)
    pf[kt] = *(const short8*)&P[wq * 16 + (lane & 15)][kt * 32 + ((lane >> 4) << 3)];

  f32x4 oacc[32];
#pragma unroll
  for (int n = 0; n < 32; ++n) oacc[n] = z;

#pragma unroll
  for (int dh = 0; dh < 2; ++dh) {
#pragma unroll
    for (int kt = 0; kt < 6; ++kt) {
#pragma unroll
      for (int i = 0; i < 4; ++i) {
        const int idx = i * 256 + tid;
        const int dr = idx >> 2, c8 = (idx & 3) << 3;
        const int t = tk0 + kt * 32 + c8;
        uint4 val = {0u, 0u, 0u, 0u};
        if (t >= 0 && t < NTOK)
          val = *(const uint4*)&vt[((long)b * DIM + dh * 256 + dr) * NTOK + t];
        *(uint4*)&vb[dr][c8] = val;
      }
      __syncthreads();
#pragma unroll
      for (int nn = 0; nn < 16; ++nn) {
        const short8 bv = *(const short8*)&vb[nn * 16 + (lane & 15)][(lane >> 4) << 3];
        mfma16(oacc[dh * 16 + nn], pf[kt], bv);
      }
      __syncthreads();
    }
  }
  asm volatile("s_nop 7\n s_nop 7\n s_nop 7");

#pragma unroll
  for (int n = 0; n < 32; ++n) {
    const int d = n * 16 + cbase;
#pragma unroll
    for (int r = 0; r < 4; ++r) {
      const long row = qrow0 + wq * 16 + rgrp + r;
      ao[row * DIM + d] = f2bf(oacc[n][r]);
    }
  }
}

// ---------- fused residual + LayerNorm, one wave per row ----------
template<int V>
__global__ __launch_bounds__(256)
void ln_kernel(const float* __restrict__ af, const u16* __restrict__ abf,
               const u16* __restrict__ bbf,
               const float* __restrict__ g, const float* __restrict__ bb,
               u16* __restrict__ obf, float* __restrict__ of)
{
  const int lane = threadIdx.x & 63;
  const long row = (long)blockIdx.x * 4 + (threadIdx.x >> 6);
  const long base = row * DIM + lane * 8;
  float x[8];
  if (V == 1) {
    const float4 u0 = *(const float4*)(af + base);
    const float4 u1 = *(const float4*)(af + base + 4);
    const uint4 ub = *(const uint4*)(bbf + base);
    x[0] = u0.x + bflo(ub.x); x[1] = u0.y + bfhi(ub.x);
    x[2] = u0.z + bflo(ub.y); x[3] = u0.w + bfhi(ub.y);
    x[4] = u1.x + bflo(ub.z); x[5] = u1.y + bfhi(ub.z);
    x[6] = u1.z + bflo(ub.w); x[7] = u1.w + bfhi(ub.w);
  } else {
    const uint4 ua = *(const uint4*)(abf + base);
    const uint4 ub = *(const uint4*)(bbf + base);
    x[0] = bflo(ua.x) + bflo(ub.x); x[1] = bfhi(ua.x) + bfhi(ub.x);
    x[2] = bflo(ua.y) + bflo(ub.y); x[3] = bfhi(ua.y) + bfhi(ub.y);
    x[4] = bflo(ua.z) + bflo(ub.z); x[5] = bfhi(ua.z) + bfhi(ub.z);
    x[6] = bflo(ua.w) + bflo(ub.w); x[7] = bfhi(ua.w) + bfhi(ub.w);
  }
  float s = 0.f, sq = 0.f;
#pragma unroll
  for (int i = 0; i < 8; ++i) { s += x[i]; sq += x[i] * x[i]; }
#pragma unroll
  for (int off = 1; off < 64; off <<= 1) {
    s += __shfl_xor(s, off, 64);
    sq += __shfl_xor(sq, off, 64);
  }
  const float mean = s * (1.f / 512.f);
  const float var = fmaxf(sq * (1.f / 512.f) - mean * mean, 0.f);
  const float rs = rsqrtf(var + 1e-5f);
  const int db = lane * 8;
  const float4 g0 = *(const float4*)(g + db);
  const float4 g1 = *(const float4*)(g + db + 4);
  const float4 b0 = *(const float4*)(bb + db);
  const float4 b1 = *(const float4*)(bb + db + 4);
  float y[8];
  y[0] = (x[0] - mean) * rs * g0.x + b0.x; y[1] = (x[1] - mean) * rs * g0.y + b0.y;
  y[2] = (x[2] - mean) * rs * g0.z + b0.z; y[3] = (x[3] - mean) * rs * g0.w + b0.w;
  y[4] = (x[4] - mean) * rs * g1.x + b1.x; y[5] = (x[5] - mean) * rs * g1.y + b1.y;
  y[6] = (x[6] - mean) * rs * g1.z + b1.z; y[7] = (x[7] - mean) * rs * g1.w + b1.w;
  if (V == 1) {
    uint4 o = { pack2(y[0], y[1]), pack2(y[2], y[3]), pack2(y[4], y[5]), pack2(y[6], y[7]) };
    *(uint4*)(obf + base) = o;
  } else {
    float4 o0v = {y[0], y[1], y[2], y[3]}, o1v = {y[4], y[5], y[6], y[7]};
    *(float4*)(of + base) = o0v;
    *(float4*)(of + base + 4) = o1v;
  }
}

// ---------- f32 -> bf16 convert ----------
__global__ __launch_bounds__(256)
void cvt_src_kernel(const float* __restrict__ in, u16* __restrict__ out)
{
  const long i = ((long)blockIdx.x * 256 + threadIdx.x) * 8;
  const float4 a = *(const float4*)(in + i);
  const float4 c = *(const float4*)(in + i + 4);
  uint4 o = { pack2(a.x, a.y), pack2(a.z, a.w), pack2(c.x, c.y), pack2(c.z, c.w) };
  *(uint4*)(out + i) = o;
}

// ---------- transpose f32(RxC) -> bf16(CxR) ----------
__global__ __launch_bounds__(256)
void transpose_cvt_kernel(const float* __restrict__ in, u16* __restrict__ out,
                          int R, int C)
{
  __shared__ float tile[32][33];
  const int tx = threadIdx.x & 31, ty = threadIdx.x >> 5;
  const long c = (long)blockIdx.x * 32 + tx;
#pragma unroll
  for (int i = 0; i < 4; ++i) {
    const long r = (long)blockIdx.y * 32 + ty + i * 8;
    tile[ty + i * 8][tx] = in[r * C + c];
  }
  __syncthreads();
#pragma unroll
  for (int i = 0; i < 4; ++i) {
    const int cc = ty + i * 8;
    out[((long)blockIdx.x * 32 + cc) * R + (long)blockIdx.y * 32 + tx] = f2bf(tile[tx][cc]);
  }
}

// ---------- transpose bf16(RxC) -> bf16(CxR), batched over z ----------
__global__ __launch_bounds__(256)
void transpose_bf_kernel(const u16* __restrict__ in, u16* __restrict__ out,
                         int R, int C)
{
  __shared__ u16 tile[32][33];
  const long bo = (long)blockIdx.z * R * C;
  const int tx = threadIdx.x & 31, ty = threadIdx.x >> 5;
  const long c = (long)blockIdx.x * 32 + tx;
#pragma unroll
  for (int i = 0; i < 4; ++i) {
    const long r = (long)blockIdx.y * 32 + ty + i * 8;
    tile[ty + i * 8][tx] = in[bo + r * C + c];
  }
  __syncthreads();
#pragma unroll
  for (int i = 0; i < 4; ++i) {
    const int cc = ty + i * 8;
    out[bo + ((long)blockIdx.x * 32 + cc) * R + (long)blockIdx.y * 32 + tx] = tile[tx][cc];
  }
}

extern "C" void kernel_launch(void* const* d_in, const int* in_sizes, int n_in,
                              void* d_out, int out_size, void* d_ws, size_t ws_size,
                              hipStream_t stream) {
  const float* src  = (const float*)d_in[0];
  const float* Wq   = (const float*)d_in[2];
  const float* bq   = (const float*)d_in[3];
  const float* Wk   = (const float*)d_in[4];
  const float* bk   = (const float*)d_in[5];
  const float* Wv   = (const float*)d_in[6];
  const float* bv   = (const float*)d_in[7];
  const float* ln1g = (const float*)d_in[8];
  const float* ln1b = (const float*)d_in[9];
  const float* W1   = (const float*)d_in[10];
  const float* b1   = (const float*)d_in[11];
  const float* W2   = (const float*)d_in[12];
  const float* b2   = (const float*)d_in[13];
  const float* ln2g = (const float*)d_in[14];
  const float* ln2b = (const float*)d_in[15];
  float* out = (float*)d_out;

  // ---- workspace overlay (~134 MiB, proven) ----
  char* ws = (char*)d_ws;
  const size_t TD2 = (size_t)32768 * 512 * 2;   // 32 MiB
  u16* buf0 = (u16*)(ws + 0 * TD2);
  u16* buf1 = (u16*)(ws + 1 * TD2);
  u16* buf2 = (u16*)(ws + 2 * TD2);
  u16* buf3 = (u16*)(ws + 3 * TD2);
  u16* wT   = (u16*)(ws + 4 * TD2);
  u16* wqkvT = wT;                       // 1536 x 512
  u16* w1T   = wT + 1536 * 512;          // 2048 x 512
  u16* w2T   = w1T + (size_t)2048 * 512; // 512 x 2048

  u16* sbf = buf0;   // src bf16
  u16* qb  = buf1;   // q (scaled)
  u16* kb  = buf2;   // k
  u16* vbf = buf3;   // v
  u16* vtb = buf0;   // v^T [b][d][tok]  (sbf dead after QKV)
  u16* aob = buf3;   // attn_out         (v dead after transpose)
  u16* xb  = buf0;   // x bf16           (vt dead after attn)
  u16* hb  = buf2;   // FF hidden chunk, 16384x2048 = buf2+buf3
  u16* yb  = buf1;   // FF2 out          (q dead after attn)

  cvt_src_kernel<<<dim3(8192), 256, 0, stream>>>(src, sbf);
  transpose_cvt_kernel<<<dim3(16, 16), 256, 0, stream>>>(Wq, wqkvT, 512, 512);
  transpose_cvt_kernel<<<dim3(16, 16), 256, 0, stream>>>(Wk, wqkvT + 512 * 512, 512, 512);
  transpose_cvt_kernel<<<dim3(16, 16), 256, 0, stream>>>(Wv, wqkvT + 1024 * 512, 512, 512);
  transpose_cvt_kernel<<<dim3(64, 16), 256, 0, stream>>>(W1, w1T, 512, 2048);
  transpose_cvt_kernel<<<dim3(16, 64), 256, 0, stream>>>(W2, w2T, 2048, 512);

  // QKV: M=32768, N=1536, K=512 -> grid (12, 128) = 1536 blocks
  gemm256_kernel<0><<<dim3(12, 128), 256, 0, stream>>>(sbf, wqkvT, 512,
                                                       bq, bk, bv, qb, kb, vbf);
  transpose_bf_kernel<<<dim3(16, 256, 4), 256, 0, stream>>>(vbf, vtb, 8192, 512);
  attn_kernel<<<dim3(128, 4), 256, 0, stream>>>(qb, kb, vtb, aob);
  ln_kernel<1><<<dim3(8192), 256, 0, stream>>>(src, nullptr, aob, ln1g, ln1b, xb, nullptr);

  // FF in two 16384-row chunks
  for (int c = 0; c < 2; ++c) {
    const size_t ro = (size_t)c * 16384;
    gemm256_kernel<1><<<dim3(16, 64), 256, 0, stream>>>(xb + ro * 512, w1T, 512,
                                                        b1, nullptr, nullptr, hb, nullptr, nullptr);
    gemm256_kernel<2><<<dim3(4, 64), 256, 0, stream>>>(hb, w2T, 2048,
                                                       b2, nullptr, nullptr, yb + ro * 512, nullptr, nullptr);
  }
  ln_kernel<2><<<dim3(8192), 256, 0, stream>>>(nullptr, xb, yb, ln2g, ln2b, nullptr, out);
}